// Round 1
// baseline (384.939 us; speedup 1.0000x reference)
//
#include <hip/hip_runtime.h>
#include <stdint.h>

#define G_SHOWERS 8192

// Workspace layout:
//   [0, 128K)   : packed uint64[2][G]  -- (beta_bits<<32)|corr_bits, atomicMax
//   [128K,192K) : esum  float [2][G]   -- atomicAdd energy
//   [192K,448K) : table float [G][8]   -- per-shower output values
// kind 0 = hits (rec_hit_id==0), kind 1 = tracks

__global__ void accum_kernel(const int* __restrict__ sid,
                             const int* __restrict__ hitid,
                             const float* __restrict__ energy,
                             const float* __restrict__ beta,
                             const float* __restrict__ corr,
                             unsigned long long* __restrict__ packed,
                             float* __restrict__ esum,
                             int n) {
    const int tid = blockIdx.x * blockDim.x + threadIdx.x;
    const int stride = gridDim.x * blockDim.x;
    const int nv = n >> 2;  // vec4 count

    for (int i = tid; i < nv; i += stride) {
        int4   s4 = reinterpret_cast<const int4*>(sid)[i];
        int4   h4 = reinterpret_cast<const int4*>(hitid)[i];
        float4 e4 = reinterpret_cast<const float4*>(energy)[i];
        float4 b4 = reinterpret_cast<const float4*>(beta)[i];
        float4 c4 = reinterpret_cast<const float4*>(corr)[i];

        const int*   sp = reinterpret_cast<const int*>(&s4);
        const int*   hp = reinterpret_cast<const int*>(&h4);
        const float* ep = reinterpret_cast<const float*>(&e4);
        const float* bp = reinterpret_cast<const float*>(&b4);
        const float* cp = reinterpret_cast<const float*>(&c4);

        #pragma unroll
        for (int j = 0; j < 4; ++j) {
            int idx = (hp[j] != 0 ? G_SHOWERS : 0) + sp[j];
            atomicAdd(&esum[idx], ep[j]);
            unsigned long long pk =
                ((unsigned long long)__float_as_uint(bp[j]) << 32) |
                (unsigned long long)__float_as_uint(cp[j]);
            atomicMax(&packed[idx], pk);
        }
    }
    // tail (n not multiple of 4)
    for (int i = nv * 4 + tid; i < n; i += stride) {
        int idx = (hitid[i] != 0 ? G_SHOWERS : 0) + sid[i];
        atomicAdd(&esum[idx], energy[i]);
        unsigned long long pk =
            ((unsigned long long)__float_as_uint(beta[i]) << 32) |
            (unsigned long long)__float_as_uint(corr[i]);
        atomicMax(&packed[idx], pk);
    }
}

__global__ void table_kernel(const unsigned long long* __restrict__ packed,
                             const float* __restrict__ esum,
                             float* __restrict__ table) {
    int g = blockIdx.x * blockDim.x + threadIdx.x;
    if (g >= G_SHOWERS) return;

    float raw_hit = esum[g];
    float raw_trk = esum[G_SHOWERS + g];
    float corr_hit = __uint_as_float((unsigned)(packed[g] & 0xffffffffull));
    float corr_trk = __uint_as_float((unsigned)(packed[G_SHOWERS + g] & 0xffffffffull));
    float cor_hit = corr_hit * raw_hit;
    float cor_trk = corr_trk * raw_trk;

    float4 lo, hi;
    lo.x = raw_trk;
    lo.y = cor_trk;
    lo.z = raw_hit;
    lo.w = cor_hit;
    hi.x = (raw_trk != 0.0f) ? raw_trk : raw_hit;   // prefer_tracks_raw
    hi.y = (cor_trk != 0.0f) ? cor_trk : cor_hit;   // prefer_tracks_corrected
    hi.z = (raw_hit != 0.0f) ? raw_hit : raw_trk;   // prefer_hits_raw
    hi.w = (cor_hit != 0.0f) ? cor_hit : cor_trk;   // prefer_hits_corrected

    reinterpret_cast<float4*>(table)[2 * g]     = lo;
    reinterpret_cast<float4*>(table)[2 * g + 1] = hi;
}

__global__ void gather_kernel(const int* __restrict__ sid,
                              const float* __restrict__ table,
                              float* __restrict__ out,
                              int n) {
    const int tid = blockIdx.x * blockDim.x + threadIdx.x;
    const int stride = gridDim.x * blockDim.x;
    const int nv = n >> 2;
    const float4* tbl = reinterpret_cast<const float4*>(table);

    for (int i = tid; i < nv; i += stride) {
        int4 s4 = reinterpret_cast<const int4*>(sid)[i];

        float4 ax = tbl[2 * s4.x], bx = tbl[2 * s4.x + 1];
        float4 ay = tbl[2 * s4.y], by = tbl[2 * s4.y + 1];
        float4 az = tbl[2 * s4.z], bz = tbl[2 * s4.z + 1];
        float4 aw = tbl[2 * s4.w], bw = tbl[2 * s4.w + 1];

        float4 p;
        // plane k, elements (x,y,z,w) of this vec4
        p.x = ax.x; p.y = ay.x; p.z = az.x; p.w = aw.x;
        reinterpret_cast<float4*>(out + 0ll * n)[i] = p;
        p.x = ax.y; p.y = ay.y; p.z = az.y; p.w = aw.y;
        reinterpret_cast<float4*>(out + 1ll * n)[i] = p;
        p.x = ax.z; p.y = ay.z; p.z = az.z; p.w = aw.z;
        reinterpret_cast<float4*>(out + 2ll * n)[i] = p;
        p.x = ax.w; p.y = ay.w; p.z = az.w; p.w = aw.w;
        reinterpret_cast<float4*>(out + 3ll * n)[i] = p;
        p.x = bx.x; p.y = by.x; p.z = bz.x; p.w = bw.x;
        reinterpret_cast<float4*>(out + 4ll * n)[i] = p;
        p.x = bx.y; p.y = by.y; p.z = bz.y; p.w = bw.y;
        reinterpret_cast<float4*>(out + 5ll * n)[i] = p;
        p.x = bx.z; p.y = by.z; p.z = bz.z; p.w = bw.z;
        reinterpret_cast<float4*>(out + 6ll * n)[i] = p;
        p.x = bx.w; p.y = by.w; p.z = bz.w; p.w = bw.w;
        reinterpret_cast<float4*>(out + 7ll * n)[i] = p;
    }
    // tail
    for (int i = nv * 4 + tid; i < n; i += stride) {
        int s = sid[i];
        #pragma unroll
        for (int k = 0; k < 8; ++k) {
            out[(long long)k * n + i] = table[8 * s + k];
        }
    }
}

extern "C" void kernel_launch(void* const* d_in, const int* in_sizes, int n_in,
                              void* d_out, int out_size, void* d_ws, size_t ws_size,
                              hipStream_t stream) {
    const int*   sid    = (const int*)d_in[0];
    const int*   hitid  = (const int*)d_in[1];
    const float* energy = (const float*)d_in[2];
    const float* beta   = (const float*)d_in[3];
    const float* corr   = (const float*)d_in[4];
    const int n = in_sizes[0];

    unsigned long long* packed = (unsigned long long*)d_ws;
    float* esum  = (float*)((char*)d_ws + 2 * G_SHOWERS * sizeof(unsigned long long));
    float* table = (float*)((char*)d_ws + 2 * G_SHOWERS * 12);

    // zero accumulators (packed + esum = 192 KB)
    hipMemsetAsync(d_ws, 0, 2 * G_SHOWERS * 12, stream);

    accum_kernel<<<2048, 256, 0, stream>>>(sid, hitid, energy, beta, corr,
                                           packed, esum, n);
    table_kernel<<<(G_SHOWERS + 255) / 256, 256, 0, stream>>>(packed, esum, table);
    gather_kernel<<<2048, 256, 0, stream>>>(sid, table, (float*)d_out, n);
}

// Round 2
// 181.783 us; speedup vs baseline: 2.1176x; 2.1176x over previous
//
#include <hip/hip_runtime.h>
#include <stdint.h>

#define G_SHOWERS 8192
#define NBINS (2 * G_SHOWERS)  // kind 0 = hits (rec_hit_id==0), kind 1 = tracks

// ws layout (nb = number of partial slabs, adaptive):
//   [0, nb*64K)        : partial slabs  u32/f32 [nb][NBINS]  (reused: bmax then esum)
//   [+0,   +64K)       : bmax_global    u32[NBINS]
//   [+64K, +128K)      : corr_global    u32[NBINS]   (memset 0 each launch)
//   [+128K,+384K)      : table          f32[G][8]

// ---------------- K1: per-block beta-max partials (LDS, no global atomics) ---
__global__ __launch_bounds__(1024) void bmax_kernel(
    const int* __restrict__ sid, const int* __restrict__ hitid,
    const float* __restrict__ beta, unsigned* __restrict__ partial, int n) {
    __shared__ unsigned bm[NBINS];
    for (int i = threadIdx.x; i < NBINS; i += blockDim.x) bm[i] = 0u;
    __syncthreads();

    const int tid = blockIdx.x * blockDim.x + threadIdx.x;
    const int stride = gridDim.x * blockDim.x;
    const int nv = n >> 2;
    for (int i = tid; i < nv; i += stride) {
        int4   s4 = reinterpret_cast<const int4*>(sid)[i];
        int4   h4 = reinterpret_cast<const int4*>(hitid)[i];
        float4 b4 = reinterpret_cast<const float4*>(beta)[i];
        const int* sp = (const int*)&s4;
        const int* hp = (const int*)&h4;
        const float* bp = (const float*)&b4;
        #pragma unroll
        for (int j = 0; j < 4; ++j) {
            int bin = (hp[j] != 0 ? G_SHOWERS : 0) + sp[j];
            atomicMax(&bm[bin], __float_as_uint(bp[j]));
        }
    }
    for (int i = nv * 4 + tid; i < n; i += stride) {
        int bin = (hitid[i] != 0 ? G_SHOWERS : 0) + sid[i];
        atomicMax(&bm[bin], __float_as_uint(beta[i]));
    }

    __syncthreads();
    unsigned* out = partial + (size_t)blockIdx.x * NBINS;
    for (int i = threadIdx.x; i < NBINS; i += blockDim.x) out[i] = bm[i];
}

// ---------------- R1: reduce bmax partials -> global -------------------------
__global__ void bmax_reduce(const unsigned* __restrict__ partial,
                            unsigned* __restrict__ bmax_g, int nb) {
    int t = blockIdx.x * blockDim.x + threadIdx.x;  // bin
    if (t >= NBINS) return;
    unsigned m = 0u;
    for (int b = 0; b < nb; ++b) m = max(m, partial[(size_t)b * NBINS + t]);
    bmax_g[t] = m;
}

// ---------------- K3: esum partials (LDS) + corr pick (sparse atomics) -------
__global__ __launch_bounds__(1024) void esum_corr_kernel(
    const int* __restrict__ sid, const int* __restrict__ hitid,
    const float* __restrict__ energy, const float* __restrict__ beta,
    const float* __restrict__ corr, const unsigned* __restrict__ bmax_g,
    float* __restrict__ partial_e, unsigned* __restrict__ corr_g, int n) {
    __shared__ float es[NBINS];
    for (int i = threadIdx.x; i < NBINS; i += blockDim.x) es[i] = 0.0f;
    __syncthreads();

    const int tid = blockIdx.x * blockDim.x + threadIdx.x;
    const int stride = gridDim.x * blockDim.x;
    const int nv = n >> 2;
    for (int i = tid; i < nv; i += stride) {
        int4   s4 = reinterpret_cast<const int4*>(sid)[i];
        int4   h4 = reinterpret_cast<const int4*>(hitid)[i];
        float4 e4 = reinterpret_cast<const float4*>(energy)[i];
        float4 b4 = reinterpret_cast<const float4*>(beta)[i];
        float4 c4 = reinterpret_cast<const float4*>(corr)[i];
        const int* sp = (const int*)&s4;
        const int* hp = (const int*)&h4;
        const float* ep = (const float*)&e4;
        const float* bp = (const float*)&b4;
        const float* cp = (const float*)&c4;
        #pragma unroll
        for (int j = 0; j < 4; ++j) {
            int bin = (hp[j] != 0 ? G_SHOWERS : 0) + sp[j];
            atomicAdd(&es[bin], ep[j]);
            unsigned bb = __float_as_uint(bp[j]);
            if (bb == __ldg(&bmax_g[bin])) {
                atomicMax(&corr_g[bin], __float_as_uint(cp[j]));  // ~16K total
            }
        }
    }
    for (int i = nv * 4 + tid; i < n; i += stride) {
        int bin = (hitid[i] != 0 ? G_SHOWERS : 0) + sid[i];
        atomicAdd(&es[bin], energy[i]);
        unsigned bb = __float_as_uint(beta[i]);
        if (bb == __ldg(&bmax_g[bin])) {
            atomicMax(&corr_g[bin], __float_as_uint(corr[i]));
        }
    }

    __syncthreads();
    float* out = partial_e + (size_t)blockIdx.x * NBINS;
    for (int i = threadIdx.x; i < NBINS; i += blockDim.x) out[i] = es[i];
}

// ---------------- K4: reduce esum partials + build per-shower table ----------
__global__ void table_kernel(const float* __restrict__ partial_e,
                             const unsigned* __restrict__ corr_g,
                             float* __restrict__ table, int nb) {
    int g = blockIdx.x * blockDim.x + threadIdx.x;
    if (g >= G_SHOWERS) return;

    float raw_hit = 0.0f, raw_trk = 0.0f;
    for (int b = 0; b < nb; ++b) {
        const float* p = partial_e + (size_t)b * NBINS;
        raw_hit += p[g];
        raw_trk += p[G_SHOWERS + g];
    }
    float corr_hit = __uint_as_float(corr_g[g]);
    float corr_trk = __uint_as_float(corr_g[G_SHOWERS + g]);
    float cor_hit = corr_hit * raw_hit;
    float cor_trk = corr_trk * raw_trk;

    float4 lo, hi;
    lo.x = raw_trk;
    lo.y = cor_trk;
    lo.z = raw_hit;
    lo.w = cor_hit;
    hi.x = (raw_trk != 0.0f) ? raw_trk : raw_hit;   // prefer_tracks_raw
    hi.y = (cor_trk != 0.0f) ? cor_trk : cor_hit;   // prefer_tracks_corrected
    hi.z = (raw_hit != 0.0f) ? raw_hit : raw_trk;   // prefer_hits_raw
    hi.w = (cor_hit != 0.0f) ? cor_hit : cor_trk;   // prefer_hits_corrected

    reinterpret_cast<float4*>(table)[2 * g]     = lo;
    reinterpret_cast<float4*>(table)[2 * g + 1] = hi;
}

// ---------------- K5: broadcast gather to 8 output planes --------------------
__global__ void gather_kernel(const int* __restrict__ sid,
                              const float* __restrict__ table,
                              float* __restrict__ out, int n) {
    const int tid = blockIdx.x * blockDim.x + threadIdx.x;
    const int stride = gridDim.x * blockDim.x;
    const int nv = n >> 2;
    const float4* tbl = reinterpret_cast<const float4*>(table);

    for (int i = tid; i < nv; i += stride) {
        int4 s4 = reinterpret_cast<const int4*>(sid)[i];

        float4 ax = tbl[2 * s4.x], bx = tbl[2 * s4.x + 1];
        float4 ay = tbl[2 * s4.y], by = tbl[2 * s4.y + 1];
        float4 az = tbl[2 * s4.z], bz = tbl[2 * s4.z + 1];
        float4 aw = tbl[2 * s4.w], bw = tbl[2 * s4.w + 1];

        float4 p;
        p.x = ax.x; p.y = ay.x; p.z = az.x; p.w = aw.x;
        reinterpret_cast<float4*>(out + 0ll * n)[i] = p;
        p.x = ax.y; p.y = ay.y; p.z = az.y; p.w = aw.y;
        reinterpret_cast<float4*>(out + 1ll * n)[i] = p;
        p.x = ax.z; p.y = ay.z; p.z = az.z; p.w = aw.z;
        reinterpret_cast<float4*>(out + 2ll * n)[i] = p;
        p.x = ax.w; p.y = ay.w; p.z = az.w; p.w = aw.w;
        reinterpret_cast<float4*>(out + 3ll * n)[i] = p;
        p.x = bx.x; p.y = by.x; p.z = bz.x; p.w = bw.x;
        reinterpret_cast<float4*>(out + 4ll * n)[i] = p;
        p.x = bx.y; p.y = by.y; p.z = bz.y; p.w = bw.y;
        reinterpret_cast<float4*>(out + 5ll * n)[i] = p;
        p.x = bx.z; p.y = by.z; p.z = bz.z; p.w = bw.z;
        reinterpret_cast<float4*>(out + 6ll * n)[i] = p;
        p.x = bx.w; p.y = by.w; p.z = bz.w; p.w = bw.w;
        reinterpret_cast<float4*>(out + 7ll * n)[i] = p;
    }
    for (int i = nv * 4 + tid; i < n; i += stride) {
        int s = sid[i];
        #pragma unroll
        for (int k = 0; k < 8; ++k) {
            out[(long long)k * n + i] = table[8 * s + k];
        }
    }
}

extern "C" void kernel_launch(void* const* d_in, const int* in_sizes, int n_in,
                              void* d_out, int out_size, void* d_ws, size_t ws_size,
                              hipStream_t stream) {
    const int*   sid    = (const int*)d_in[0];
    const int*   hitid  = (const int*)d_in[1];
    const float* energy = (const float*)d_in[2];
    const float* beta   = (const float*)d_in[3];
    const float* corr   = (const float*)d_in[4];
    const int n = in_sizes[0];

    const size_t slab_bytes = (size_t)NBINS * 4;            // 64 KB
    const size_t fixed_bytes = 6 * slab_bytes;              // bmax_g + corr_g + table(4 slabs)
    int nb = 256;
    if (ws_size < (size_t)nb * slab_bytes + fixed_bytes) {
        size_t avail = (ws_size > fixed_bytes) ? (ws_size - fixed_bytes) : slab_bytes;
        nb = (int)(avail / slab_bytes);
        if (nb < 8) nb = 8;   // assume ws is at least ~0.9 MB
    }

    char* base = (char*)d_ws;
    unsigned* partial_b = (unsigned*)base;                       // reused as f32 later
    float*    partial_e = (float*)base;
    unsigned* bmax_g    = (unsigned*)(base + (size_t)nb * slab_bytes);
    unsigned* corr_g    = (unsigned*)((char*)bmax_g + slab_bytes);
    float*    table     = (float*)((char*)corr_g + slab_bytes);

    // corr accumulator must start at 0 every call
    hipMemsetAsync(corr_g, 0, slab_bytes, stream);

    bmax_kernel<<<nb, 1024, 0, stream>>>(sid, hitid, beta, partial_b, n);
    bmax_reduce<<<(NBINS + 255) / 256, 256, 0, stream>>>(partial_b, bmax_g, nb);
    esum_corr_kernel<<<nb, 1024, 0, stream>>>(sid, hitid, energy, beta, corr,
                                              bmax_g, partial_e, corr_g, n);
    table_kernel<<<(G_SHOWERS + 255) / 256, 256, 0, stream>>>(partial_e, corr_g, table, nb);
    gather_kernel<<<2048, 256, 0, stream>>>(sid, table, (float*)d_out, n);
}

// Round 4
// 84.885 us; speedup vs baseline: 4.5348x; 2.1415x over previous
//
#include <hip/hip_runtime.h>
#include <stdint.h>

#define G_SHOWERS 8192
#define NBINS (2 * G_SHOWERS)  // bin = kind*8192 + sid; kind: 0=hits, 1=tracks

typedef float f32x4 __attribute__((ext_vector_type(4)));

// ws layout (nb slabs, one shared slab region reused by both element passes):
//   [0, nb*64K)   : partial slabs u32/f32 [nb][NBINS]
//   [+0,   +64K)  : bmax_g u32[NBINS]
//   [+64K, +128K) : corr_g u32[NBINS]   (zeroed by bmax_kernel block 0)
//   [+128K,+384K) : table  f32[G][8]

// ---- K1: per-block beta-max partials in LDS; block 0 also zeroes corr_g ----
__global__ __launch_bounds__(1024) void bmax_kernel(
    const int* __restrict__ sid, const int* __restrict__ hitid,
    const float* __restrict__ beta, unsigned* __restrict__ partial,
    unsigned* __restrict__ corr_g, int n) {
    __shared__ unsigned bm[NBINS];
    for (int i = threadIdx.x; i < NBINS; i += 1024) bm[i] = 0u;
    if (blockIdx.x == 0) {
        for (int i = threadIdx.x; i < NBINS; i += 1024) corr_g[i] = 0u;
    }
    __syncthreads();

    const int tid = blockIdx.x * blockDim.x + threadIdx.x;
    const int stride = gridDim.x * blockDim.x;
    const int nv = n >> 2;
    for (int i = tid; i < nv; i += stride) {
        int4   s4 = reinterpret_cast<const int4*>(sid)[i];
        int4   h4 = reinterpret_cast<const int4*>(hitid)[i];
        float4 b4 = reinterpret_cast<const float4*>(beta)[i];
        const int* sp = (const int*)&s4;
        const int* hp = (const int*)&h4;
        const float* bp = (const float*)&b4;
        #pragma unroll
        for (int j = 0; j < 4; ++j) {
            int bin = (hp[j] != 0 ? G_SHOWERS : 0) + sp[j];
            atomicMax(&bm[bin], __float_as_uint(bp[j]));
        }
    }
    for (int i = nv * 4 + tid; i < n; i += stride) {
        int bin = (hitid[i] != 0 ? G_SHOWERS : 0) + sid[i];
        atomicMax(&bm[bin], __float_as_uint(beta[i]));
    }

    __syncthreads();
    unsigned* out = partial + (size_t)blockIdx.x * NBINS;
    for (int i = threadIdx.x; i < NBINS; i += 1024) out[i] = bm[i];
}

// ---- R1: reduce bmax partials, 4 quarter-chains per bin, coalesced ---------
__global__ __launch_bounds__(256) void bmax_reduce(
    const unsigned* __restrict__ partial, unsigned* __restrict__ bmax_g, int nb) {
    const int q = threadIdx.x >> 6;       // 0..3
    const int lane = threadIdx.x & 63;
    const int bin = blockIdx.x * 64 + lane;
    unsigned m = 0u;
    #pragma unroll 8
    for (int b = q; b < nb; b += 4)
        m = max(m, partial[(size_t)b * NBINS + bin]);
    __shared__ unsigned red[4][64];
    red[q][lane] = m;
    __syncthreads();
    if (q == 0) {
        m = max(max(red[0][lane], red[1][lane]),
                max(red[2][lane], red[3][lane]));
        bmax_g[bin] = m;
    }
}

// ---- K3: esum partials in LDS + sparse corr atomicMax ----------------------
__global__ __launch_bounds__(1024) void esum_corr_kernel(
    const int* __restrict__ sid, const int* __restrict__ hitid,
    const float* __restrict__ energy, const float* __restrict__ beta,
    const float* __restrict__ corr, const unsigned* __restrict__ bmax_g,
    float* __restrict__ partial_e, unsigned* __restrict__ corr_g, int n) {
    __shared__ float es[NBINS];
    for (int i = threadIdx.x; i < NBINS; i += 1024) es[i] = 0.0f;
    __syncthreads();

    const int tid = blockIdx.x * blockDim.x + threadIdx.x;
    const int stride = gridDim.x * blockDim.x;
    const int nv = n >> 2;
    for (int i = tid; i < nv; i += stride) {
        int4   s4 = reinterpret_cast<const int4*>(sid)[i];
        int4   h4 = reinterpret_cast<const int4*>(hitid)[i];
        float4 e4 = reinterpret_cast<const float4*>(energy)[i];
        float4 b4 = reinterpret_cast<const float4*>(beta)[i];
        float4 c4 = reinterpret_cast<const float4*>(corr)[i];
        const int* sp = (const int*)&s4;
        const int* hp = (const int*)&h4;
        const float* ep = (const float*)&e4;
        const float* bp = (const float*)&b4;
        const float* cp = (const float*)&c4;
        #pragma unroll
        for (int j = 0; j < 4; ++j) {
            int bin = (hp[j] != 0 ? G_SHOWERS : 0) + sp[j];
            atomicAdd(&es[bin], ep[j]);
            if (__float_as_uint(bp[j]) == __ldg(&bmax_g[bin])) {
                atomicMax(&corr_g[bin], __float_as_uint(cp[j]));  // ~16K total
            }
        }
    }
    for (int i = nv * 4 + tid; i < n; i += stride) {
        int bin = (hitid[i] != 0 ? G_SHOWERS : 0) + sid[i];
        atomicAdd(&es[bin], energy[i]);
        if (__float_as_uint(beta[i]) == __ldg(&bmax_g[bin])) {
            atomicMax(&corr_g[bin], __float_as_uint(corr[i]));
        }
    }

    __syncthreads();
    float* out = partial_e + (size_t)blockIdx.x * NBINS;
    for (int i = threadIdx.x; i < NBINS; i += 1024) out[i] = es[i];
}

// ---- T: reduce esum partials (4 chains/shower, coalesced) + build table ----
__global__ __launch_bounds__(256) void table_kernel(
    const float* __restrict__ partial_e, const unsigned* __restrict__ corr_g,
    float* __restrict__ table, int nb) {
    const int q = threadIdx.x >> 6;
    const int lane = threadIdx.x & 63;
    const int g = blockIdx.x * 64 + lane;  // shower
    float ah = 0.0f, at = 0.0f;
    #pragma unroll 8
    for (int b = q; b < nb; b += 4) {
        const float* p = partial_e + (size_t)b * NBINS;
        ah += p[g];
        at += p[G_SHOWERS + g];
    }
    __shared__ float rh[4][64], rt[4][64];
    rh[q][lane] = ah;
    rt[q][lane] = at;
    __syncthreads();
    if (q == 0) {
        float raw_hit = rh[0][lane] + rh[1][lane] + rh[2][lane] + rh[3][lane];
        float raw_trk = rt[0][lane] + rt[1][lane] + rt[2][lane] + rt[3][lane];
        float corr_hit = __uint_as_float(corr_g[g]);
        float corr_trk = __uint_as_float(corr_g[G_SHOWERS + g]);
        float cor_hit = corr_hit * raw_hit;
        float cor_trk = corr_trk * raw_trk;

        float4 lo, hi;
        lo.x = raw_trk;
        lo.y = cor_trk;
        lo.z = raw_hit;
        lo.w = cor_hit;
        hi.x = (raw_trk != 0.0f) ? raw_trk : raw_hit;
        hi.y = (cor_trk != 0.0f) ? cor_trk : cor_hit;
        hi.z = (raw_hit != 0.0f) ? raw_hit : raw_trk;
        hi.w = (cor_hit != 0.0f) ? cor_hit : cor_trk;

        reinterpret_cast<float4*>(table)[2 * g]     = lo;
        reinterpret_cast<float4*>(table)[2 * g + 1] = hi;
    }
}

// ---- G: broadcast gather to 8 output planes (nontemporal stores) -----------
__global__ void gather_kernel(const int* __restrict__ sid,
                              const float* __restrict__ table,
                              float* __restrict__ out, int n) {
    const int tid = blockIdx.x * blockDim.x + threadIdx.x;
    const int stride = gridDim.x * blockDim.x;
    const int nv = n >> 2;
    const float4* tbl = reinterpret_cast<const float4*>(table);

    for (int i = tid; i < nv; i += stride) {
        int4 s4 = reinterpret_cast<const int4*>(sid)[i];

        float4 ax = tbl[2 * s4.x], bx = tbl[2 * s4.x + 1];
        float4 ay = tbl[2 * s4.y], by = tbl[2 * s4.y + 1];
        float4 az = tbl[2 * s4.z], bz = tbl[2 * s4.z + 1];
        float4 aw = tbl[2 * s4.w], bw = tbl[2 * s4.w + 1];

        f32x4 p;
        p.x = ax.x; p.y = ay.x; p.z = az.x; p.w = aw.x;
        __builtin_nontemporal_store(p, reinterpret_cast<f32x4*>(out + 0ll * n) + i);
        p.x = ax.y; p.y = ay.y; p.z = az.y; p.w = aw.y;
        __builtin_nontemporal_store(p, reinterpret_cast<f32x4*>(out + 1ll * n) + i);
        p.x = ax.z; p.y = ay.z; p.z = az.z; p.w = aw.z;
        __builtin_nontemporal_store(p, reinterpret_cast<f32x4*>(out + 2ll * n) + i);
        p.x = ax.w; p.y = ay.w; p.z = az.w; p.w = aw.w;
        __builtin_nontemporal_store(p, reinterpret_cast<f32x4*>(out + 3ll * n) + i);
        p.x = bx.x; p.y = by.x; p.z = bz.x; p.w = bw.x;
        __builtin_nontemporal_store(p, reinterpret_cast<f32x4*>(out + 4ll * n) + i);
        p.x = bx.y; p.y = by.y; p.z = bz.y; p.w = bw.y;
        __builtin_nontemporal_store(p, reinterpret_cast<f32x4*>(out + 5ll * n) + i);
        p.x = bx.z; p.y = by.z; p.z = bz.z; p.w = bw.z;
        __builtin_nontemporal_store(p, reinterpret_cast<f32x4*>(out + 6ll * n) + i);
        p.x = bx.w; p.y = by.w; p.z = bz.w; p.w = bw.w;
        __builtin_nontemporal_store(p, reinterpret_cast<f32x4*>(out + 7ll * n) + i);
    }
    for (int i = nv * 4 + tid; i < n; i += stride) {
        int s = sid[i];
        #pragma unroll
        for (int k = 0; k < 8; ++k) {
            out[(long long)k * n + i] = table[8 * s + k];
        }
    }
}

extern "C" void kernel_launch(void* const* d_in, const int* in_sizes, int n_in,
                              void* d_out, int out_size, void* d_ws, size_t ws_size,
                              hipStream_t stream) {
    const int*   sid    = (const int*)d_in[0];
    const int*   hitid  = (const int*)d_in[1];
    const float* energy = (const float*)d_in[2];
    const float* beta   = (const float*)d_in[3];
    const float* corr   = (const float*)d_in[4];
    const int n = in_sizes[0];

    const size_t slab_bytes = (size_t)NBINS * 4;            // 64 KB
    const size_t fixed_bytes = 6 * slab_bytes;              // bmax_g + corr_g + table
    int nb = 256;
    if (ws_size < (size_t)nb * slab_bytes + fixed_bytes) {
        size_t avail = (ws_size > fixed_bytes) ? (ws_size - fixed_bytes) : slab_bytes;
        nb = (int)(avail / slab_bytes) & ~3;  // multiple of 4
        if (nb < 8) nb = 8;
    }

    char* base = (char*)d_ws;
    unsigned* partial_b = (unsigned*)base;   // slab region reused by both passes
    float*    partial_e = (float*)base;
    unsigned* bmax_g    = (unsigned*)(base + (size_t)nb * slab_bytes);
    unsigned* corr_g    = (unsigned*)((char*)bmax_g + slab_bytes);
    float*    table     = (float*)((char*)corr_g + slab_bytes);

    bmax_kernel<<<nb, 1024, 0, stream>>>(sid, hitid, beta, partial_b, corr_g, n);
    bmax_reduce<<<NBINS / 64, 256, 0, stream>>>(partial_b, bmax_g, nb);
    esum_corr_kernel<<<nb, 1024, 0, stream>>>(sid, hitid, energy, beta, corr,
                                              bmax_g, partial_e, corr_g, n);
    table_kernel<<<G_SHOWERS / 64, 256, 0, stream>>>(partial_e, corr_g, table, nb);
    gather_kernel<<<2048, 256, 0, stream>>>(sid, table, (float*)d_out, n);
}